// Round 4
// baseline (35.932 us; speedup 1.0000x reference)
//
#include <hip/hip_runtime.h>
#include <hip/hip_bf16.h>

// Guided attention loss:
//   guided(b,x,y) = 1 - exp(-(y/il - x/ol)^2 / (2*sigma^2)),  sigma=0.4
//   e = (x<ol && y<il) ? guided * att : 0
//   out[b]     = sum(e)   / ol     (l1_mae)
//   out[B+b]   = sum(e^2) / ol     (l2_mse)
//
// Shapes fixed by setup_inputs(): B=64, T_out=2048, T_in=512.

#define GA_B     64
#define GA_TOUT  2048
#define GA_TIN   512
#define ROWS_PER_BLOCK 32
#define BLOCK_THREADS  256
#define INV_2SIGMA2 3.125f   // 1/(2*0.4^2)

__device__ __forceinline__ void block_reduce2(float& l1, float& l2) {
    // wave64 butterfly-down reduce
    #pragma unroll
    for (int o = 32; o > 0; o >>= 1) {
        l1 += __shfl_down(l1, o, 64);
        l2 += __shfl_down(l2, o, 64);
    }
    __shared__ float s1[BLOCK_THREADS / 64];
    __shared__ float s2[BLOCK_THREADS / 64];
    const int lane = threadIdx.x & 63;
    const int wave = threadIdx.x >> 6;
    if (lane == 0) { s1[wave] = l1; s2[wave] = l2; }
    __syncthreads();
    if (threadIdx.x == 0) {
        l1 = s1[0] + s1[1] + s1[2] + s1[3];
        l2 = s2[0] + s2[1] + s2[2] + s2[3];
    }
}

__global__ __launch_bounds__(BLOCK_THREADS)
void ga_partial_kernel(const float* __restrict__ att,
                       const int* __restrict__ ilens,
                       const int* __restrict__ olens,
                       float* __restrict__ part) {
    const int b       = blockIdx.y;
    const int rowBase = blockIdx.x * ROWS_PER_BLOCK;
    const int ol      = olens[b];
    const int il      = ilens[b];

    float l1 = 0.0f, l2 = 0.0f;

    const int rowEnd = min(rowBase + ROWS_PER_BLOCK, ol);
    if (rowBase < rowEnd) {
        const float inv_il = 1.0f / (float)il;
        const float inv_ol = 1.0f / (float)ol;
        const int   nv     = (il + 3) >> 2;   // float4 chunks per row (<= 128)
        const float4* __restrict__ base =
            (const float4*)(att + (size_t)b * GA_TOUT * GA_TIN);

        for (int x = rowBase; x < rowEnd; ++x) {
            const float gx = (float)x * inv_ol;
            const float4* __restrict__ rowp = base + (size_t)x * (GA_TIN / 4);
            for (int v = threadIdx.x; v < nv; v += BLOCK_THREADS) {
                const float4 a = rowp[v];
                const int y0 = v << 2;
                #pragma unroll
                for (int j = 0; j < 4; ++j) {
                    const int   y  = y0 + j;
                    const float av = (j == 0) ? a.x : (j == 1) ? a.y
                                   : (j == 2) ? a.z : a.w;
                    const float t  = (float)y * inv_il - gx;
                    const float g  = 1.0f - __expf(-(t * t) * INV_2SIGMA2);
                    const float e  = (y < il) ? g * av : 0.0f;
                    l1 += e;
                    l2 += e * e;
                }
            }
        }
    }

    block_reduce2(l1, l2);
    if (threadIdx.x == 0) {
        const int pidx = (b * gridDim.x + blockIdx.x) * 2;
        part[pidx + 0] = l1;
        part[pidx + 1] = l2;
    }
}

__global__ __launch_bounds__(64)
void ga_final_kernel(const float* __restrict__ part,
                     const int* __restrict__ olens,
                     float* __restrict__ out,
                     int chunks) {
    const int b = blockIdx.x;
    const int t = threadIdx.x;
    float l1 = 0.0f, l2 = 0.0f;
    for (int c = t; c < chunks; c += 64) {
        l1 += part[(b * chunks + c) * 2 + 0];
        l2 += part[(b * chunks + c) * 2 + 1];
    }
    #pragma unroll
    for (int o = 32; o > 0; o >>= 1) {
        l1 += __shfl_down(l1, o, 64);
        l2 += __shfl_down(l2, o, 64);
    }
    if (t == 0) {
        const float d = (float)olens[b];
        out[b]        = l1 / d;
        out[GA_B + b] = l2 / d;
    }
}

extern "C" void kernel_launch(void* const* d_in, const int* in_sizes, int n_in,
                              void* d_out, int out_size, void* d_ws, size_t ws_size,
                              hipStream_t stream) {
    const float* att   = (const float*)d_in[0];
    const int*   ilens = (const int*)d_in[1];
    const int*   olens = (const int*)d_in[2];
    float*       out   = (float*)d_out;
    float*       part  = (float*)d_ws;   // 4096 blocks * 2 floats = 32 KB

    const int rowChunks = GA_TOUT / ROWS_PER_BLOCK;  // 64
    dim3 grid1(rowChunks, GA_B);
    ga_partial_kernel<<<grid1, BLOCK_THREADS, 0, stream>>>(att, ilens, olens, part);
    ga_final_kernel<<<GA_B, 64, 0, stream>>>(part, olens, out, rowChunks);
}

// Round 5
// 26.435 us; speedup vs baseline: 1.3593x; 1.3593x over previous
//
#include <hip/hip_runtime.h>
#include <hip/hip_bf16.h>

// Guided attention loss:
//   guided(b,x,y) = 1 - exp(-(y/il - x/ol)^2 / (2*sigma^2)),  sigma=0.4
//   e = (x<ol && y<il) ? guided * att : 0
//   out[b]   = sum(e)   / ol     (l1_mae)
//   out[B+b] = sum(e^2) / ol     (l2_mse)
//
// Shapes fixed by setup_inputs(): B=64, T_out=2048, T_in=512.
//
// Structure (round 5): wave-per-row. Block = 256 thr = 4 waves, each wave
// owns ROWS_PER_WAVE=4 consecutive rows; lane covers float4 chunks {lane,
// lane+64} (nv <= 128 always). All 8 loads issued before compute -> high
// MLP per wave; previously only wave 0 loaded (v-loop thread-indexed with
// nv<=128) and 32 rows were serial on it -> latency-bound at ~3x roofline.

#define GA_B     64
#define GA_TOUT  2048
#define GA_TIN   512
#define ROWS_PER_WAVE  4
#define WAVES_PER_BLOCK 4
#define ROWS_PER_BLOCK (ROWS_PER_WAVE * WAVES_PER_BLOCK)   // 16
#define BLOCK_THREADS  256
#define INV_2SIGMA2 3.125f   // 1/(2*0.4^2)

__device__ __forceinline__ void block_reduce2(float& l1, float& l2) {
    #pragma unroll
    for (int o = 32; o > 0; o >>= 1) {
        l1 += __shfl_down(l1, o, 64);
        l2 += __shfl_down(l2, o, 64);
    }
    __shared__ float s1[WAVES_PER_BLOCK];
    __shared__ float s2[WAVES_PER_BLOCK];
    const int lane = threadIdx.x & 63;
    const int wave = threadIdx.x >> 6;
    if (lane == 0) { s1[wave] = l1; s2[wave] = l2; }
    __syncthreads();
    if (threadIdx.x == 0) {
        l1 = s1[0] + s1[1] + s1[2] + s1[3];
        l2 = s2[0] + s2[1] + s2[2] + s2[3];
    }
}

__global__ __launch_bounds__(BLOCK_THREADS)
void ga_partial_kernel(const float* __restrict__ att,
                       const int* __restrict__ ilens,
                       const int* __restrict__ olens,
                       float* __restrict__ part) {
    const int b    = blockIdx.y;
    const int lane = threadIdx.x & 63;
    const int wave = threadIdx.x >> 6;
    const int waveRow = blockIdx.x * ROWS_PER_BLOCK + wave * ROWS_PER_WAVE;

    const int ol = olens[b];
    const int il = ilens[b];
    const int nv = (il + 3) >> 2;           // float4 chunks per row, <= 128

    float l1 = 0.0f, l2 = 0.0f;

    if (waveRow < ol) {
        const float inv_il = 1.0f / (float)il;
        const float inv_ol = 1.0f / (float)ol;
        const float4* __restrict__ base =
            (const float4*)(att + (size_t)b * GA_TOUT * GA_TIN);

        // ---- load phase: up to 8 float4 loads in flight per lane ----
        float4 A0[ROWS_PER_WAVE], A1[ROWS_PER_WAVE];
        #pragma unroll
        for (int r = 0; r < ROWS_PER_WAVE; ++r) {
            A0[r] = make_float4(0.f, 0.f, 0.f, 0.f);
            A1[r] = make_float4(0.f, 0.f, 0.f, 0.f);
            const int x = waveRow + r;
            if (x < ol) {
                const float4* __restrict__ rowp = base + (size_t)x * (GA_TIN / 4);
                if (lane < nv)      A0[r] = rowp[lane];
                if (lane + 64 < nv) A1[r] = rowp[lane + 64];
            }
        }

        // ---- compute phase ----
        #pragma unroll
        for (int r = 0; r < ROWS_PER_WAVE; ++r) {
            const int x = waveRow + r;
            if (x < ol) {
                const float gx = (float)x * inv_ol;
                #pragma unroll
                for (int h = 0; h < 2; ++h) {
                    const float4 a  = (h == 0) ? A0[r] : A1[r];
                    const int    y0 = (lane << 2) + (h << 8);
                    #pragma unroll
                    for (int j = 0; j < 4; ++j) {
                        const int   y  = y0 + j;
                        const float av = (j == 0) ? a.x : (j == 1) ? a.y
                                       : (j == 2) ? a.z : a.w;
                        const float t  = (float)y * inv_il - gx;
                        const float g  = 1.0f - __expf(-(t * t) * INV_2SIGMA2);
                        const float e  = (y < il) ? g * av : 0.0f;
                        l1 += e;
                        l2 += e * e;
                    }
                }
            }
        }
    }

    block_reduce2(l1, l2);
    if (threadIdx.x == 0) {
        const int pidx = (b * gridDim.x + blockIdx.x) * 2;
        part[pidx + 0] = l1;
        part[pidx + 1] = l2;
    }
}

__global__ __launch_bounds__(64)
void ga_final_kernel(const float* __restrict__ part,
                     const int* __restrict__ olens,
                     float* __restrict__ out,
                     int chunks) {
    const int b = blockIdx.x;
    const int t = threadIdx.x;
    float l1 = 0.0f, l2 = 0.0f;
    for (int c = t; c < chunks; c += 64) {
        l1 += part[(b * chunks + c) * 2 + 0];
        l2 += part[(b * chunks + c) * 2 + 1];
    }
    #pragma unroll
    for (int o = 32; o > 0; o >>= 1) {
        l1 += __shfl_down(l1, o, 64);
        l2 += __shfl_down(l2, o, 64);
    }
    if (t == 0) {
        const float d = (float)olens[b];
        out[b]        = l1 / d;
        out[GA_B + b] = l2 / d;
    }
}

extern "C" void kernel_launch(void* const* d_in, const int* in_sizes, int n_in,
                              void* d_out, int out_size, void* d_ws, size_t ws_size,
                              hipStream_t stream) {
    const float* att   = (const float*)d_in[0];
    const int*   ilens = (const int*)d_in[1];
    const int*   olens = (const int*)d_in[2];
    float*       out   = (float*)d_out;
    float*       part  = (float*)d_ws;   // 64 batches * 128 chunks * 2 floats = 64 KB

    const int rowChunks = GA_TOUT / ROWS_PER_BLOCK;  // 128
    dim3 grid1(rowChunks, GA_B);
    ga_partial_kernel<<<grid1, BLOCK_THREADS, 0, stream>>>(att, ilens, olens, part);
    ga_final_kernel<<<GA_B, 64, 0, stream>>>(part, olens, out, rowChunks);
}

// Round 6
// 25.942 us; speedup vs baseline: 1.3851x; 1.0190x over previous
//
#include <hip/hip_runtime.h>
#include <hip/hip_bf16.h>

// Guided attention loss:
//   guided(b,x,y) = 1 - exp(-(y/il - x/ol)^2 / (2*sigma^2)),  sigma=0.4
//   e = (x<ol && y<il) ? guided * att : 0
//   out[b]   = sum(e)   / ol     (l1_mae)
//   out[B+b] = sum(e^2) / ol     (l2_mse)
//
// Shapes fixed: B=64, T_out=2048, T_in=512.
//
// Round 6: 8 rows/wave (16 float4 loads in flight), hoisted per-lane column
// terms (y/il scaled) + masks, exp2-based guided (1 trans + 6 VALU per elem),
// wave-uniform skip of cols 256..511 when il<=256. k2: 64 chunks -> one
// float2 per lane.

#define GA_B     64
#define GA_TOUT  2048
#define GA_TIN   512
#define ROWS_PER_WAVE   8
#define WAVES_PER_BLOCK 4
#define ROWS_PER_BLOCK  (ROWS_PER_WAVE * WAVES_PER_BLOCK)   // 32
#define BLOCK_THREADS   256
#define GRID_X          (GA_TOUT / ROWS_PER_BLOCK)           // 64
// KS = sqrt(3.125 * log2(e)):  2^(-(KS*z)^2) = exp(-z^2 * 3.125)
#define KS 2.1233046f

__global__ __launch_bounds__(BLOCK_THREADS)
void ga_partial_kernel(const float* __restrict__ att,
                       const int* __restrict__ ilens,
                       const int* __restrict__ olens,
                       float* __restrict__ part) {
    const int b    = blockIdx.y;
    const int lane = threadIdx.x & 63;
    const int wave = threadIdx.x >> 6;
    const int waveRow = blockIdx.x * ROWS_PER_BLOCK + wave * ROWS_PER_WAVE;

    const int ol = olens[b];
    const int il = ilens[b];
    const int nv = (il + 3) >> 2;            // float4 chunks per row, <= 128

    float l1 = 0.0f, l2 = 0.0f;

    if (waveRow < ol) {
        const float inv_il_s = KS / (float)il;
        const float inv_ol_s = KS / (float)ol;
        const bool  hi       = (nv > 64);     // any of cols 256..511 valid?
        const float4* __restrict__ base =
            (const float4*)(att + (size_t)b * GA_TOUT * GA_TIN);

        // ---- hoisted per-lane column constants (once per block) ----
        float ys0[4], ys1[4], m0[4], m1[4];
        #pragma unroll
        for (int j = 0; j < 4; ++j) {
            const int y0 = (lane << 2) + j;
            const int y1 = y0 + 256;
            ys0[j] = (float)y0 * inv_il_s;
            ys1[j] = (float)y1 * inv_il_s;
            m0[j]  = (y0 < il) ? 1.0f : 0.0f;
            m1[j]  = (y1 < il) ? 1.0f : 0.0f;
        }

        // ---- load phase: up to 16 float4 loads in flight per lane ----
        float4 A0[ROWS_PER_WAVE], A1[ROWS_PER_WAVE];
        #pragma unroll
        for (int r = 0; r < ROWS_PER_WAVE; ++r) {
            A0[r] = make_float4(0.f, 0.f, 0.f, 0.f);
            A1[r] = make_float4(0.f, 0.f, 0.f, 0.f);
            const int x = waveRow + r;
            if (x < ol) {
                const float4* __restrict__ rowp = base + (size_t)x * (GA_TIN / 4);
                if (lane < nv)              A0[r] = rowp[lane];
                if (hi && (lane + 64 < nv)) A1[r] = rowp[lane + 64];
            }
        }

        // ---- compute phase ----
        #pragma unroll
        for (int r = 0; r < ROWS_PER_WAVE; ++r) {
            const int   x   = waveRow + r;
            const float gxs = (float)x * inv_ol_s;
            {
                const float4 a = A0[r];
                #pragma unroll
                for (int j = 0; j < 4; ++j) {
                    const float av = (j == 0) ? a.x : (j == 1) ? a.y
                                   : (j == 2) ? a.z : a.w;
                    const float w  = ys0[j] - gxs;
                    const float E  = exp2f(-w * w);
                    const float q  = av - av * E;       // guided * att
                    const float e  = q * m0[j];
                    l1 += e;
                    l2 += e * e;
                }
            }
            if (hi) {
                const float4 a = A1[r];
                #pragma unroll
                for (int j = 0; j < 4; ++j) {
                    const float av = (j == 0) ? a.x : (j == 1) ? a.y
                                   : (j == 2) ? a.z : a.w;
                    const float w  = ys1[j] - gxs;
                    const float E  = exp2f(-w * w);
                    const float q  = av - av * E;
                    const float e  = q * m1[j];
                    l1 += e;
                    l2 += e * e;
                }
            }
        }
    }

    // ---- block reduce (4 waves) ----
    #pragma unroll
    for (int o = 32; o > 0; o >>= 1) {
        l1 += __shfl_down(l1, o, 64);
        l2 += __shfl_down(l2, o, 64);
    }
    __shared__ float s1[WAVES_PER_BLOCK];
    __shared__ float s2[WAVES_PER_BLOCK];
    if (lane == 0) { s1[wave] = l1; s2[wave] = l2; }
    __syncthreads();
    if (threadIdx.x == 0) {
        l1 = s1[0] + s1[1] + s1[2] + s1[3];
        l2 = s2[0] + s2[1] + s2[2] + s2[3];
        const int pidx = (b * GRID_X + blockIdx.x) * 2;
        part[pidx + 0] = l1;
        part[pidx + 1] = l2;
    }
}

__global__ __launch_bounds__(64)
void ga_final_kernel(const float* __restrict__ part,
                     const int* __restrict__ olens,
                     float* __restrict__ out) {
    const int b = blockIdx.x;
    const int t = threadIdx.x;
    // one float2 per lane: exactly GRID_X=64 chunks per batch
    const float2 p = ((const float2*)part)[b * GRID_X + t];
    float l1 = p.x, l2 = p.y;
    #pragma unroll
    for (int o = 32; o > 0; o >>= 1) {
        l1 += __shfl_down(l1, o, 64);
        l2 += __shfl_down(l2, o, 64);
    }
    if (t == 0) {
        const float d = (float)olens[b];
        out[b]        = l1 / d;
        out[GA_B + b] = l2 / d;
    }
}

extern "C" void kernel_launch(void* const* d_in, const int* in_sizes, int n_in,
                              void* d_out, int out_size, void* d_ws, size_t ws_size,
                              hipStream_t stream) {
    const float* att   = (const float*)d_in[0];
    const int*   ilens = (const int*)d_in[1];
    const int*   olens = (const int*)d_in[2];
    float*       out   = (float*)d_out;
    float*       part  = (float*)d_ws;   // 64 batches * 64 chunks * 2 floats = 32 KB

    dim3 grid1(GRID_X, GA_B);
    ga_partial_kernel<<<grid1, BLOCK_THREADS, 0, stream>>>(att, ilens, olens, part);
    ga_final_kernel<<<GA_B, 64, 0, stream>>>(part, olens, out);
}